// Round 1
// baseline (10415.985 us; speedup 1.0000x reference)
//
#include <hip/hip_runtime.h>
#include <hip/hip_bf16.h>
#include <math.h>

typedef __hip_bfloat16 bf16;

__device__ __forceinline__ float sigf(float x) { return 1.f / (1.f + expf(-x)); }

template<typename T> __device__ __forceinline__ T cvt_out(float v);
template<> __device__ __forceinline__ float cvt_out<float>(float v) { return v; }
template<> __device__ __forceinline__ bf16  cvt_out<bf16>(float v)  { return __float2bfloat16(v); }

// ---------------- patch extraction: X[512,3,32,32] -> v_fw[64,512,48] ----------------
__global__ void patch_kernel(const float* __restrict__ X, float* __restrict__ v) {
  int idx = blockIdx.x * 256 + threadIdx.x;   // exactly 64*512*48 threads
  int k = idx % 48;
  int b = (idx / 48) % 512;
  int t = idx / (48 * 512);
  int c = k >> 4, r = (k >> 2) & 3, s = k & 3;
  int ph = t & 7, pw = t >> 3;
  v[idx] = X[((b * 3 + c) * 32 + ph * 4 + r) * 32 + pw * 4 + s];
}

// ---------------- generic GEMM: C[m,n] = act(A[M,K] @ W[N,K]^T + b1 + b2) ----------------
// 64x64 block tile, 256 threads, 4x4 per thread, K-chunk 16.
template<typename OutT, bool RELU>
__global__ __launch_bounds__(256) void gemm_nt(
    const float* __restrict__ A, const float* __restrict__ W,
    const float* __restrict__ b1, const float* __restrict__ b2,
    OutT* __restrict__ C, int M, int N, int K, int ldc) {
  __shared__ float As[16][68];   // [k][m], pad 68 keeps float4 alignment, 2-way banks (free)
  __shared__ float Ws[16][68];   // [k][n]
  int tid = threadIdx.x;
  int tx = tid & 15, ty = tid >> 4;
  int m0 = blockIdx.y << 6, n0 = blockIdx.x << 6;
  const float* Ap = A + (size_t)m0 * K;
  const float* Wp = W + (size_t)n0 * K;
  float acc[4][4] = {};
  for (int k0 = 0; k0 < K; k0 += 16) {
#pragma unroll
    for (int i = 0; i < 4; i++) {
      int idx = tid + (i << 8);
      int row = idx >> 4, col = idx & 15;
      As[col][row] = Ap[(size_t)row * K + k0 + col];
      Ws[col][row] = Wp[(size_t)row * K + k0 + col];
    }
    __syncthreads();
#pragma unroll
    for (int kk = 0; kk < 16; kk++) {
      float4 av = *(const float4*)&As[kk][ty << 2];
      float4 wv = *(const float4*)&Ws[kk][tx << 2];
      float a[4] = {av.x, av.y, av.z, av.w};
      float w[4] = {wv.x, wv.y, wv.z, wv.w};
#pragma unroll
      for (int i = 0; i < 4; i++)
#pragma unroll
        for (int j = 0; j < 4; j++) acc[i][j] += a[i] * w[j];
    }
    __syncthreads();
  }
#pragma unroll
  for (int i = 0; i < 4; i++) {
    int m = m0 + (ty << 2) + i;
#pragma unroll
    for (int j = 0; j < 4; j++) {
      int n = n0 + (tx << 2) + j;
      float v = acc[i][j];
      if (b1) v += b1[n];
      if (b2) v += b2[n];
      if (RELU) v = fmaxf(v, 0.f);
      C[(size_t)m * ldc + n] = cvt_out<OutT>(v);
    }
  }
}

// ---------------- one LSTM time step for a pair of independent LSTMs ----------------
// grid (10, 16, 2), block 256. Block: 32 batch rows x 32 hidden x 4 gates, K=320.
__global__ __launch_bounds__(256) void lstm_step(
    const bf16* __restrict__ xgF, const bf16* __restrict__ xgR,
    const float* __restrict__ WhhA, const float* __restrict__ WhhB,
    const float* __restrict__ hinA, float* __restrict__ houtA, float* __restrict__ cA,
    const float* __restrict__ hinB, float* __restrict__ houtB, float* __restrict__ cB,
    float* __restrict__ outA, float* __restrict__ outB, int ldo) {
  int lst = blockIdx.z;
  const bf16* xg  = lst ? xgR  : xgF;
  const float* Whh = lst ? WhhB : WhhA;
  const float* hin = lst ? hinB : hinA;
  float* hout = lst ? houtB : houtA;
  float* c    = lst ? cB    : cA;
  float* out  = lst ? outB  : outA;
  int j0 = blockIdx.x << 5;      // hidden tile
  int r0 = blockIdx.y << 5;      // batch tile
  __shared__ float Hs[32][33];   // [k][row]
  __shared__ float Ws[32][130];  // [k][g*32+jj]
  int tid = threadIdx.x;
  int tx = tid & 15, ty = tid >> 4;
  float acc[4][4] = {};          // [gate][i*2+j]
  for (int k0 = 0; k0 < 320; k0 += 32) {
#pragma unroll
    for (int i = 0; i < 4; i++) {
      int idx = tid + (i << 8);
      int row = idx >> 5, col = idx & 31;
      Hs[col][row] = hin[(size_t)(r0 + row) * 320 + k0 + col];
    }
#pragma unroll
    for (int i = 0; i < 16; i++) {
      int idx = tid + (i << 8);
      int wrow = idx >> 5, col = idx & 31;
      int g = wrow >> 5, jj = wrow & 31;
      Ws[col][wrow] = Whh[(size_t)(g * 320 + j0 + jj) * 320 + k0 + col];
    }
    __syncthreads();
#pragma unroll
    for (int kk = 0; kk < 32; kk++) {
      float a0 = Hs[kk][ty * 2], a1 = Hs[kk][ty * 2 + 1];
#pragma unroll
      for (int g = 0; g < 4; g++) {
        float w0 = Ws[kk][g * 32 + tx * 2], w1 = Ws[kk][g * 32 + tx * 2 + 1];
        acc[g][0] += a0 * w0; acc[g][1] += a0 * w1;
        acc[g][2] += a1 * w0; acc[g][3] += a1 * w1;
      }
    }
    __syncthreads();
  }
#pragma unroll
  for (int i = 0; i < 2; i++) {
    int r = r0 + ty * 2 + i;
#pragma unroll
    for (int j = 0; j < 2; j++) {
      int jh = j0 + tx * 2 + j;
      size_t xb = (size_t)r * 1280 + jh;
      float gi = acc[0][i*2+j] + __bfloat162float(xg[xb]);
      float gf = acc[1][i*2+j] + __bfloat162float(xg[xb + 320]);
      float gg = acc[2][i*2+j] + __bfloat162float(xg[xb + 640]);
      float go = acc[3][i*2+j] + __bfloat162float(xg[xb + 960]);
      float iv = sigf(gi), fv = sigf(gf), gv = tanhf(gg), ov = sigf(go);
      size_t sb = (size_t)r * 320 + jh;
      float cn = fv * c[sb] + iv * gv;
      float hn = ov * tanhf(cn);
      c[sb] = cn;
      hout[sb] = hn;
      out[(size_t)r * ldo + jh] = hn;
    }
  }
}

// ---------------- conv1 (3x3) + relu + maxpool2 fused: X -> pool[512,128,15,15] ----------------
__global__ __launch_bounds__(256) void conv1_pool(
    const float* __restrict__ X, const float* __restrict__ w,
    const float* __restrict__ bias, float* __restrict__ pool) {
  int b = blockIdx.x;
  __shared__ float Xs[3 * 32 * 32];
  __shared__ float Wl[128 * 27];
  __shared__ float Bl[128];
  int tid = threadIdx.x;
  for (int i = tid; i < 3072; i += 256) Xs[i] = X[(size_t)b * 3072 + i];
  for (int i = tid; i < 3456; i += 256) Wl[i] = w[i];
  if (tid < 128) Bl[tid] = bias[tid];
  __syncthreads();
  int oc = tid & 127, half = tid >> 7;
  float wr[27];
#pragma unroll
  for (int q = 0; q < 27; q++) wr[q] = Wl[oc * 27 + q];
  float bv = Bl[oc];
  for (int p = half; p < 225; p += 2) {
    int i = p / 15, j = p % 15;
    float mx = -3.4e38f;
#pragma unroll
    for (int dy = 0; dy < 2; dy++)
#pragma unroll
      for (int dx = 0; dx < 2; dx++) {
        float s = bv;
        int rb = 2 * i + dy, cb = 2 * j + dx;
#pragma unroll
        for (int cc = 0; cc < 3; cc++)
#pragma unroll
          for (int kr = 0; kr < 3; kr++)
#pragma unroll
            for (int kc = 0; kc < 3; kc++)
              s += wr[cc * 9 + kr * 3 + kc] * Xs[cc * 1024 + (rb + kr) * 32 + cb + kc];
        mx = fmaxf(mx, s);
      }
    pool[((size_t)(b * 128 + oc)) * 225 + p] = fmaxf(mx, 0.f);
  }
}

// ---------------- per-channel batchnorm stats -> fold to a*x+s ----------------
__global__ void bn_stats(const float* __restrict__ x, int C, int per, int B,
                         const float* __restrict__ g, const float* __restrict__ bb,
                         float* __restrict__ a, float* __restrict__ s) {
  int c = blockIdx.x;
  int n = B * per;
  float sum = 0.f, sq = 0.f;
  for (int i = threadIdx.x; i < n; i += 256) {
    int b = i / per, p = i - b * per;
    float v = x[((size_t)b * C + c) * per + p];
    sum += v; sq += v * v;
  }
  __shared__ float S1[256], S2[256];
  S1[threadIdx.x] = sum; S2[threadIdx.x] = sq;
  __syncthreads();
  for (int off = 128; off > 0; off >>= 1) {
    if (threadIdx.x < off) { S1[threadIdx.x] += S1[threadIdx.x + off]; S2[threadIdx.x] += S2[threadIdx.x + off]; }
    __syncthreads();
  }
  if (threadIdx.x == 0) {
    float m = S1[0] / n;
    float var = S2[0] / n - m * m;
    float av = g[c] * rsqrtf(var + 1e-5f);
    a[c] = av; s[c] = bb[c] - m * av;
  }
}

__global__ void bn_apply(float* __restrict__ x, const float* __restrict__ a,
                         const float* __restrict__ s, int per, int C, size_t total) {
  size_t i = (size_t)blockIdx.x * 256 + threadIdx.x;
  if (i < total) {
    int c = (int)((i / per) % C);
    x[i] = a[c] * x[i] + s[c];
  }
}

// ---------------- conv2 (4x4, 128->48) with bn1 applied on load, relu on store ----------------
// grid (3 rowgroups, 512 b), block 192 = 48 oc x 4 out rows.
__global__ __launch_bounds__(192) void conv2_kernel(
    const float* __restrict__ pool, const float* __restrict__ w,
    const float* __restrict__ bias, const float* __restrict__ a1,
    const float* __restrict__ s1, float* __restrict__ out) {
  int rg = blockIdx.x, b = blockIdx.y;
  int r0 = rg * 4;
  __shared__ float L[128 * 7 * 15];   // 53.76 KB
  int tid = threadIdx.x;
#pragma unroll
  for (int i = 0; i < 70; i++) {
    int idx = tid + i * 192;
    int c = idx / 105, rem = idx % 105;
    int r = rem / 15, col = rem % 15;
    L[idx] = pool[((size_t)(b * 128 + c)) * 225 + (r0 + r) * 15 + col] * a1[c] + s1[c];
  }
  __syncthreads();
  int oc = tid % 48, orow = tid / 48;   // orow 0..3
  float acc[12];
  float bv = bias[oc];
#pragma unroll
  for (int j = 0; j < 12; j++) acc[j] = bv;
  for (int c = 0; c < 128; c++) {
#pragma unroll
    for (int kr = 0; kr < 4; kr++) {
      float v[15];
#pragma unroll
      for (int q = 0; q < 15; q++) v[q] = L[(c * 7 + orow + kr) * 15 + q];
      const float* wp = &w[((size_t)(oc * 128 + c)) * 16 + kr * 4];
#pragma unroll
      for (int kc = 0; kc < 4; kc++) {
        float wv = wp[kc];
#pragma unroll
        for (int j = 0; j < 12; j++) acc[j] += wv * v[j + kc];
      }
    }
  }
  float* op = &out[((size_t)(b * 48 + oc)) * 144 + (r0 + orow) * 12];
#pragma unroll
  for (int j = 0; j < 12; j++) op[j] = fmaxf(acc[j], 0.f);
}

// ---------------- fc + log_softmax: outcat[512,4096] @ fc_w[10,4096]^T ----------------
__global__ __launch_bounds__(64) void fc_logsoftmax(
    const float* __restrict__ A, const float* __restrict__ W,
    const float* __restrict__ bias, float* __restrict__ out) {
  int b = blockIdx.x, lane = threadIdx.x;
  float acc[10] = {};
  for (int k = lane; k < 4096; k += 64) {
    float x = A[(size_t)b * 4096 + k];
#pragma unroll
    for (int o = 0; o < 10; o++) acc[o] += x * W[o * 4096 + k];
  }
#pragma unroll
  for (int o = 0; o < 10; o++)
    for (int off = 32; off > 0; off >>= 1) acc[o] += __shfl_down(acc[o], off);
  if (lane == 0) {
    float l[10];
    float m = -3.4e38f;
#pragma unroll
    for (int o = 0; o < 10; o++) { l[o] = acc[o] + bias[o]; m = fmaxf(m, l[o]); }
    float se = 0.f;
#pragma unroll
    for (int o = 0; o < 10; o++) se += expf(l[o] - m);
    float ls = logf(se);
#pragma unroll
    for (int o = 0; o < 10; o++) out[b * 10 + o] = l[o] - m - ls;
  }
}

__global__ void zero_k(float* __restrict__ p, size_t n) {
  size_t i = (size_t)blockIdx.x * 256 + threadIdx.x;
  if (i < n) p[i] = 0.f;
}

extern "C" void kernel_launch(void* const* d_in, const int* in_sizes, int n_in,
                              void* d_out, int out_size, void* d_ws, size_t ws_size,
                              hipStream_t stream) {
  const float* X    = (const float*)d_in[0];
  const float* c1w  = (const float*)d_in[1];
  const float* c1b  = (const float*)d_in[2];
  const float* bn1g = (const float*)d_in[3];
  const float* bn1b = (const float*)d_in[4];
  const float* c2w  = (const float*)d_in[5];
  const float* c2b  = (const float*)d_in[6];
  const float* bn2g = (const float*)d_in[7];
  const float* bn2b = (const float*)d_in[8];
  const float *Wih[4], *Whh[4], *bih[4], *bhh[4];
  for (int i = 0; i < 4; i++) {
    Wih[i] = (const float*)d_in[9 + 4 * i];
    Whh[i] = (const float*)d_in[10 + 4 * i];
    bih[i] = (const float*)d_in[11 + 4 * i];
    bhh[i] = (const float*)d_in[12 + 4 * i];
  }
  const float* d1w = (const float*)d_in[25];
  const float* d1b = (const float*)d_in[26];
  const float* d2w = (const float*)d_in[27];
  const float* d2b = (const float*)d_in[28];
  const float* fcw = (const float*)d_in[29];
  const float* fcb = (const float*)d_in[30];
  float* out = (float*)d_out;

  // ---- workspace layout (354 MB total) ----
  char* p = (char*)d_ws;
  float* v_fw  = (float*)p;  p += (size_t)64 * 512 * 48 * 4;      // 6.3 MB
  bf16*  xgA   = (bf16*)p;   p += (size_t)64 * 512 * 1280 * 2;    // 83.9 MB (bf16)
  bf16*  xgB   = (bf16*)p;   p += (size_t)64 * 512 * 1280 * 2;    // 83.9 MB
  float* h_fw  = (float*)p;  p += (size_t)64 * 512 * 640 * 4;     // 83.9 MB
  float* hfm   = (float*)p;  p += (size_t)512 * 40960 * 4;        // 83.9 MB
  float* states= (float*)p;  p += (size_t)6 * 512 * 320 * 4;      // 3.9 MB
  float* outcat= (float*)p;  p += (size_t)512 * 4096 * 4;         // 8.4 MB
  float* bnp   = (float*)p;  p += 512 * 4;
  // conv buffers alias the xg region (dead after phase-B scan)
  float* pool  = (float*)xgA;   // 512*128*225 fp32 = 59 MB <= 83.9 MB
  float* c2out = (float*)xgB;   // 512*48*144 fp32 = 14.2 MB
  float* a1 = bnp, *s1 = bnp + 128, *a2 = bnp + 256, *s2 = bnp + 304;

  float* hA0 = states;            float* hA1 = hA0 + 163840; float* cA = hA1 + 163840;
  float* hB0 = cA + 163840;       float* hB1 = hB0 + 163840; float* cB = hB1 + 163840;

  // 1) patches
  patch_kernel<<<6144, 256, 0, stream>>>(X, v_fw);

  // 2) input projections for LSTM pair 1/2 (bias folded, bf16 out)
  gemm_nt<bf16, false><<<dim3(20, 512), 256, 0, stream>>>(v_fw, Wih[0], bih[0], bhh[0], xgA, 32768, 1280, 48, 1280);
  gemm_nt<bf16, false><<<dim3(20, 512), 256, 0, stream>>>(v_fw, Wih[1], bih[1], bhh[1], xgB, 32768, 1280, 48, 1280);

  // 3) phase A scan (LSTM1 fwd + LSTM2 on reversed sequence)
  zero_k<<<3840, 256, 0, stream>>>(states, (size_t)6 * 163840);
  for (int t = 0; t < 64; t++) {
    const bf16* xf = xgA + (size_t)t * 512 * 1280;
    const bf16* xr = xgB + (size_t)(63 - t) * 512 * 1280;
    float* hiA = (t & 1) ? hA1 : hA0;  float* hoA = (t & 1) ? hA0 : hA1;
    float* hiB = (t & 1) ? hB1 : hB0;  float* hoB = (t & 1) ? hB0 : hB1;
    float* oA = h_fw + (size_t)t * 512 * 640;
    lstm_step<<<dim3(10, 16, 2), 256, 0, stream>>>(xf, xr, Whh[0], Whh[1],
        hiA, hoA, cA, hiB, hoB, cB, oA, oA + 320, 640);
  }

  // 4) input projections for LSTM pair 3/4 (overwrite xg region)
  gemm_nt<bf16, false><<<dim3(20, 512), 256, 0, stream>>>(h_fw, Wih[2], bih[2], bhh[2], xgA, 32768, 1280, 640, 1280);
  gemm_nt<bf16, false><<<dim3(20, 512), 256, 0, stream>>>(h_fw, Wih[3], bih[3], bhh[3], xgB, 32768, 1280, 640, 1280);

  // 5) phase B scan -> hfm[b, t*640 + f]
  zero_k<<<3840, 256, 0, stream>>>(states, (size_t)6 * 163840);
  for (int t = 0; t < 64; t++) {
    const bf16* xf = xgA + (size_t)t * 512 * 1280;
    const bf16* xr = xgB + (size_t)(63 - t) * 512 * 1280;
    float* hiA = (t & 1) ? hA1 : hA0;  float* hoA = (t & 1) ? hA0 : hA1;
    float* hiB = (t & 1) ? hB1 : hB0;  float* hoB = (t & 1) ? hB0 : hB1;
    float* oA = hfm + (size_t)t * 640;
    lstm_step<<<dim3(10, 16, 2), 256, 0, stream>>>(xf, xr, Whh[2], Whh[3],
        hiA, hoA, cA, hiB, hoB, cB, oA, oA + 320, 40960);
  }

  // 6) dense1 -> outcat[:, 0:2048]
  gemm_nt<float, true><<<dim3(32, 8), 256, 0, stream>>>(hfm, d1w, d1b, nullptr, outcat, 512, 2048, 40960, 4096);

  // 7) conv branch (xg region now dead -> pool/c2out alias it)
  conv1_pool<<<512, 256, 0, stream>>>(X, c1w, c1b, pool);
  bn_stats<<<128, 256, 0, stream>>>(pool, 128, 225, 512, bn1g, bn1b, a1, s1);
  conv2_kernel<<<dim3(3, 512), 192, 0, stream>>>(pool, c2w, c2b, a1, s1, c2out);
  bn_stats<<<48, 256, 0, stream>>>(c2out, 48, 144, 512, bn2g, bn2b, a2, s2);
  bn_apply<<<(3538944 + 255) / 256, 256, 0, stream>>>(c2out, a2, s2, 144, 48, (size_t)3538944);

  // 8) dense2 -> outcat[:, 2048:4096]
  gemm_nt<float, true><<<dim3(32, 8), 256, 0, stream>>>(c2out, d2w, d2b, nullptr, outcat + 2048, 512, 2048, 6912, 4096);

  // 9) fc + log_softmax -> d_out [512,10]
  fc_logsoftmax<<<512, 64, 0, stream>>>(outcat, fcw, fcb, out);
}

// Round 2
// 3960.539 us; speedup vs baseline: 2.6299x; 2.6299x over previous
//
#include <hip/hip_runtime.h>
#include <hip/hip_bf16.h>
#include <math.h>

typedef __hip_bfloat16 bf16;
typedef short bf16x8 __attribute__((ext_vector_type(8)));   // 8 bf16 = 4 VGPRs
typedef float f32x4 __attribute__((ext_vector_type(4)));

__device__ __forceinline__ float sigf(float x) { return 1.f / (1.f + expf(-x)); }

template<typename T> __device__ __forceinline__ T cvt_out(float v);
template<> __device__ __forceinline__ float cvt_out<float>(float v) { return v; }
template<> __device__ __forceinline__ bf16  cvt_out<bf16>(float v)  { return __float2bfloat16(v); }

__device__ __forceinline__ unsigned short f2bu(float x) {
  bf16 b = __float2bfloat16(x);
  return *reinterpret_cast<unsigned short*>(&b);
}

// async global->LDS, 16B per lane. LDS dest must be wave-uniform-base + lane*16.
__device__ __forceinline__ void load_lds16(const void* g, void* l) {
  __builtin_amdgcn_global_load_lds(
      (const __attribute__((address_space(1))) unsigned int*)g,
      (__attribute__((address_space(3))) unsigned int*)l,
      16, 0, 0);
}

// ---------------- patch extraction: X[512,3,32,32] -> v_fw[64,512,48] f32 ----------------
__global__ void patch_kernel(const float* __restrict__ X, float* __restrict__ v) {
  int idx = blockIdx.x * 256 + threadIdx.x;
  int k = idx % 48;
  int b = (idx / 48) % 512;
  int t = idx / (48 * 512);
  int c = k >> 4, r = (k >> 2) & 3, s = k & 3;
  int ph = t & 7, pw = t >> 3;
  v[idx] = X[((b * 3 + c) * 32 + ph * 4 + r) * 32 + pw * 4 + s];
}

// ---------------- fp32 -> bf16 convert (x4 vectorized) ----------------
__global__ __launch_bounds__(256) void cvt_f32_bf16_k(const float* __restrict__ in,
                                                      bf16* __restrict__ out, size_t n4) {
  size_t i = (size_t)blockIdx.x * 256 + threadIdx.x;
  if (i >= n4) return;
  float4 v = ((const float4*)in)[i];
  ushort4 o;
  o.x = f2bu(v.x); o.y = f2bu(v.y); o.z = f2bu(v.z); o.w = f2bu(v.w);
  ((ushort4*)out)[i] = o;
}

// ---------------- legacy fp32 GEMM (only for xg1/xg2, K=48): C = A@W^T + b1 + b2 ----------------
template<typename OutT, bool RELU>
__global__ __launch_bounds__(256) void gemm_nt(
    const float* __restrict__ A, const float* __restrict__ W,
    const float* __restrict__ b1, const float* __restrict__ b2,
    OutT* __restrict__ C, int M, int N, int K, int ldc) {
  __shared__ float As[16][68];
  __shared__ float Ws[16][68];
  int tid = threadIdx.x;
  int tx = tid & 15, ty = tid >> 4;
  int m0 = blockIdx.y << 6, n0 = blockIdx.x << 6;
  const float* Ap = A + (size_t)m0 * K;
  const float* Wp = W + (size_t)n0 * K;
  float acc[4][4] = {};
  for (int k0 = 0; k0 < K; k0 += 16) {
#pragma unroll
    for (int i = 0; i < 4; i++) {
      int idx = tid + (i << 8);
      int row = idx >> 4, col = idx & 15;
      As[col][row] = Ap[(size_t)row * K + k0 + col];
      Ws[col][row] = Wp[(size_t)row * K + k0 + col];
    }
    __syncthreads();
#pragma unroll
    for (int kk = 0; kk < 16; kk++) {
      float4 av = *(const float4*)&As[kk][ty << 2];
      float4 wv = *(const float4*)&Ws[kk][tx << 2];
      float a[4] = {av.x, av.y, av.z, av.w};
      float w[4] = {wv.x, wv.y, wv.z, wv.w};
#pragma unroll
      for (int i = 0; i < 4; i++)
#pragma unroll
        for (int j = 0; j < 4; j++) acc[i][j] += a[i] * w[j];
    }
    __syncthreads();
  }
#pragma unroll
  for (int i = 0; i < 4; i++) {
    int m = m0 + (ty << 2) + i;
#pragma unroll
    for (int j = 0; j < 4; j++) {
      int n = n0 + (tx << 2) + j;
      float v = acc[i][j];
      if (b1) v += b1[n];
      if (b2) v += b2[n];
      if (RELU) v = fmaxf(v, 0.f);
      C[(size_t)m * ldc + n] = cvt_out<OutT>(v);
    }
  }
}

// ---------------- bf16 MFMA GEMM (NT): C[M,N] = A[M,K] @ W[N,K]^T (+bias) ----------------
// 128x128 tile, 256 threads = 4 waves (2x2 of 64x64), BK=32, global_load_lds staging.
// Requires M%128==0, N%128==0, K%32==0. SPLITK: C is float partial buffer [z][M][N].
template<typename OutT, bool RELU, bool SPLITK>
__global__ __launch_bounds__(256) void gemm_mfma(
    const bf16* __restrict__ A, const bf16* __restrict__ W,
    const float* __restrict__ b1, const float* __restrict__ b2,
    OutT* __restrict__ C, int M, int N, int K, int ldc, int ksplit) {
  __shared__ __align__(16) short As[128 * 32];
  __shared__ __align__(16) short Ws[128 * 32];
  int tid = threadIdx.x;
  int m0 = blockIdx.y << 7, n0 = blockIdx.x << 7;
  int kb = SPLITK ? blockIdx.z * ksplit : 0;
  int ke = SPLITK ? kb + ksplit : K;
  int w = tid >> 6, lane = tid & 63;
  int wm = (w >> 1) << 6, wn = (w & 1) << 6;
  int lm = lane & 15, quad = lane >> 4;
  f32x4 acc[4][4];
  f32x4 z4 = {0.f, 0.f, 0.f, 0.f};
#pragma unroll
  for (int i = 0; i < 4; i++)
#pragma unroll
    for (int j = 0; j < 4; j++) acc[i][j] = z4;

  int srow = tid >> 2;          // 0..63
  int soff = (tid & 3) * 8;     // bf16 elems within K-chunk
  const bf16* Ab  = A + (size_t)(m0 + srow) * K + kb + soff;
  const bf16* Ab2 = Ab + (size_t)64 * K;
  const bf16* Wb  = W + (size_t)(n0 + srow) * K + kb + soff;
  const bf16* Wb2 = Wb + (size_t)64 * K;
  short* AL  = &As[(size_t)tid * 8];
  short* AL2 = &As[(size_t)(tid + 256) * 8];
  short* WL  = &Ws[(size_t)tid * 8];
  short* WL2 = &Ws[(size_t)(tid + 256) * 8];

  for (int k0 = kb; k0 < ke; k0 += 32) {
    load_lds16(Ab, AL);  load_lds16(Ab2, AL2);
    load_lds16(Wb, WL);  load_lds16(Wb2, WL2);
    Ab += 32; Ab2 += 32; Wb += 32; Wb2 += 32;
    __syncthreads();   // vmcnt(0) drain -> LDS valid
    bf16x8 af[4], wf[4];
#pragma unroll
    for (int i = 0; i < 4; i++) af[i] = *(const bf16x8*)&As[(wm + i * 16 + lm) * 32 + quad * 8];
#pragma unroll
    for (int j = 0; j < 4; j++) wf[j] = *(const bf16x8*)&Ws[(wn + j * 16 + lm) * 32 + quad * 8];
#pragma unroll
    for (int i = 0; i < 4; i++)
#pragma unroll
      for (int j = 0; j < 4; j++)
        acc[i][j] = __builtin_amdgcn_mfma_f32_16x16x32_bf16(af[i], wf[j], acc[i][j], 0, 0, 0);
    __syncthreads();   // protect LDS before next overwrite
  }

  if (SPLITK) {
    float* P = (float*)C + (size_t)blockIdx.z * M * N;
#pragma unroll
    for (int i = 0; i < 4; i++)
#pragma unroll
      for (int j = 0; j < 4; j++) {
        int col = n0 + wn + j * 16 + lm;
        int rowb = m0 + wm + i * 16 + quad * 4;
#pragma unroll
        for (int r = 0; r < 4; r++)
          P[(size_t)(rowb + r) * N + col] = acc[i][j][r];
      }
  } else {
#pragma unroll
    for (int i = 0; i < 4; i++)
#pragma unroll
      for (int j = 0; j < 4; j++) {
        int col = n0 + wn + j * 16 + lm;
        int rowb = m0 + wm + i * 16 + quad * 4;
        float bias = (b1 ? b1[col] : 0.f) + (b2 ? b2[col] : 0.f);
#pragma unroll
        for (int r = 0; r < 4; r++) {
          float v = acc[i][j][r] + bias;
          if (RELU) v = fmaxf(v, 0.f);
          C[(size_t)(rowb + r) * ldc + col] = cvt_out<OutT>(v);
        }
      }
  }
}

// ---------------- split-K reduce + bias + relu ----------------
__global__ __launch_bounds__(256) void splitk_reduce(const float* __restrict__ P,
                                                     const float* __restrict__ bias,
                                                     float* __restrict__ out,
                                                     int MN, int N, int ldc, int nz) {
  int i = blockIdx.x * 256 + threadIdx.x;
  if (i >= MN) return;
  int m = i / N, n = i - m * N;
  float s = bias[n];
  for (int z = 0; z < nz; z++) s += P[(size_t)z * MN + i];
  out[(size_t)m * ldc + n] = fmaxf(s, 0.f);
}

// ---------------- MFMA LSTM step: 2 independent LSTMs (z), M=512, H=320, K=320 ----------------
// grid (10 j-tiles of 32, 8 m-tiles of 64, 2 lstm). block 256 = 4 waves, wave = gate.
// h kept as bf16 hi+lo pair for recurrence accuracy: gates = Whh@(h_hi) + Whh@(h_lo) + xg.
__global__ __launch_bounds__(256) void lstm_step_mfma(
    const bf16* __restrict__ xgF, const bf16* __restrict__ xgR,
    const bf16* __restrict__ WhhA, const bf16* __restrict__ WhhB,
    const bf16* __restrict__ hinA_hi, const bf16* __restrict__ hinA_lo,
    bf16* __restrict__ houtA_hi, bf16* __restrict__ houtA_lo, float* __restrict__ cA,
    const bf16* __restrict__ hinB_hi, const bf16* __restrict__ hinB_lo,
    bf16* __restrict__ houtB_hi, bf16* __restrict__ houtB_lo, float* __restrict__ cB,
    bf16* __restrict__ outA, bf16* __restrict__ outB, int ldo) {
  int lst = blockIdx.z;
  const bf16* xg  = lst ? xgR : xgF;
  const bf16* Whh = lst ? WhhB : WhhA;
  const bf16* hhi = lst ? hinB_hi : hinA_hi;
  const bf16* hlo = lst ? hinB_lo : hinA_lo;
  bf16* hohi = lst ? houtB_hi : houtA_hi;
  bf16* holo = lst ? houtB_lo : houtA_lo;
  float* c   = lst ? cB : cA;
  bf16* out  = lst ? outB : outA;
  int j0 = blockIdx.x << 5;   // hidden tile base (32 wide)
  int r0 = blockIdx.y << 6;   // batch tile base (64 rows)

  __shared__ __align__(16) short Ah[64 * 32];
  __shared__ __align__(16) short Al[64 * 32];
  __shared__ __align__(16) short Bs[128 * 32];
  __shared__ float G[64 * 129];   // gate preacts, pad 129 (bank-conflict-free epilogue reads)

  int tid = threadIdx.x;
  int g = tid >> 6, lane = tid & 63;
  int lm = lane & 15, quad = lane >> 4;
  f32x4 acc[4][2];
  f32x4 z4 = {0.f, 0.f, 0.f, 0.f};
#pragma unroll
  for (int i = 0; i < 4; i++) { acc[i][0] = z4; acc[i][1] = z4; }

  int srow = tid >> 2;           // 0..63
  int soff = (tid & 3) * 8;
  const bf16* Ahb = hhi + (size_t)(r0 + srow) * 320 + soff;
  const bf16* Alb = hlo + (size_t)(r0 + srow) * 320 + soff;
  int br1 = tid >> 2;            // LDS B rows 0..63
  int br2 = br1 + 64;            // 64..127
  int grow1 = (br1 >> 5) * 320 + j0 + (br1 & 31);
  int grow2 = (br2 >> 5) * 320 + j0 + (br2 & 31);
  const bf16* Bb1 = Whh + (size_t)grow1 * 320 + soff;
  const bf16* Bb2 = Whh + (size_t)grow2 * 320 + soff;
  short* AhL = &Ah[(size_t)tid * 8];
  short* AlL = &Al[(size_t)tid * 8];
  short* BL1 = &Bs[(size_t)tid * 8];
  short* BL2 = &Bs[(size_t)(tid + 256) * 8];

  for (int k0 = 0; k0 < 320; k0 += 32) {
    load_lds16(Ahb, AhL); load_lds16(Alb, AlL);
    load_lds16(Bb1, BL1); load_lds16(Bb2, BL2);
    Ahb += 32; Alb += 32; Bb1 += 32; Bb2 += 32;
    __syncthreads();
    bf16x8 ah[4], alv[4], bv[2];
#pragma unroll
    for (int i = 0; i < 4; i++) {
      ah[i]  = *(const bf16x8*)&Ah[(i * 16 + lm) * 32 + quad * 8];
      alv[i] = *(const bf16x8*)&Al[(i * 16 + lm) * 32 + quad * 8];
    }
#pragma unroll
    for (int j = 0; j < 2; j++) bv[j] = *(const bf16x8*)&Bs[(g * 32 + j * 16 + lm) * 32 + quad * 8];
#pragma unroll
    for (int i = 0; i < 4; i++)
#pragma unroll
      for (int j = 0; j < 2; j++) {
        acc[i][j] = __builtin_amdgcn_mfma_f32_16x16x32_bf16(ah[i],  bv[j], acc[i][j], 0, 0, 0);
        acc[i][j] = __builtin_amdgcn_mfma_f32_16x16x32_bf16(alv[i], bv[j], acc[i][j], 0, 0, 0);
      }
    __syncthreads();
  }

  // scatter gate preacts to LDS: row 0..63 (batch-local), col g*32 + 0..31
#pragma unroll
  for (int i = 0; i < 4; i++)
#pragma unroll
    for (int j = 0; j < 2; j++)
#pragma unroll
      for (int r = 0; r < 4; r++)
        G[(i * 16 + quad * 4 + r) * 129 + g * 32 + j * 16 + lm] = acc[i][j][r];
  __syncthreads();

  // pointwise: thread -> row rl = tid>>2, 8 consecutive hidden cols
  int rl = tid >> 2;
  int jb = (tid & 3) * 8;
  int r = r0 + rl;
#pragma unroll
  for (int q = 0; q < 8; q++) {
    int jl = jb + q;          // 0..31 local hidden
    int jh = j0 + jl;         // global hidden
    float pre[4];
#pragma unroll
    for (int g2 = 0; g2 < 4; g2++)
      pre[g2] = G[rl * 129 + g2 * 32 + jl] +
                __bfloat162float(xg[(size_t)r * 1280 + g2 * 320 + jh]);
    float iv = sigf(pre[0]), fv = sigf(pre[1]), gv = tanhf(pre[2]), ov = sigf(pre[3]);
    size_t sb = (size_t)r * 320 + jh;
    float cn = fv * c[sb] + iv * gv;
    float hn = ov * tanhf(cn);
    c[sb] = cn;
    bf16 hb = __float2bfloat16(hn);
    hohi[sb] = hb;
    holo[sb] = __float2bfloat16(hn - __bfloat162float(hb));
    out[(size_t)r * ldo + jh] = hb;
  }
}

// ---------------- conv1 (3x3) + relu + maxpool2 fused ----------------
__global__ __launch_bounds__(256) void conv1_pool(
    const float* __restrict__ X, const float* __restrict__ w,
    const float* __restrict__ bias, float* __restrict__ pool) {
  int b = blockIdx.x;
  __shared__ float Xs[3 * 32 * 32];
  __shared__ float Wl[128 * 27];
  __shared__ float Bl[128];
  int tid = threadIdx.x;
  for (int i = tid; i < 3072; i += 256) Xs[i] = X[(size_t)b * 3072 + i];
  for (int i = tid; i < 3456; i += 256) Wl[i] = w[i];
  if (tid < 128) Bl[tid] = bias[tid];
  __syncthreads();
  int oc = tid & 127, half = tid >> 7;
  float wr[27];
#pragma unroll
  for (int q = 0; q < 27; q++) wr[q] = Wl[oc * 27 + q];
  float bv = Bl[oc];
  for (int p = half; p < 225; p += 2) {
    int i = p / 15, j = p % 15;
    float mx = -3.4e38f;
#pragma unroll
    for (int dy = 0; dy < 2; dy++)
#pragma unroll
      for (int dx = 0; dx < 2; dx++) {
        float s = bv;
        int rb = 2 * i + dy, cb = 2 * j + dx;
#pragma unroll
        for (int cc = 0; cc < 3; cc++)
#pragma unroll
          for (int kr = 0; kr < 3; kr++)
#pragma unroll
            for (int kc = 0; kc < 3; kc++)
              s += wr[cc * 9 + kr * 3 + kc] * Xs[cc * 1024 + (rb + kr) * 32 + cb + kc];
        mx = fmaxf(mx, s);
      }
    pool[((size_t)(b * 128 + oc)) * 225 + p] = fmaxf(mx, 0.f);
  }
}

// ---------------- batchnorm stats -> fold to a*x+s ----------------
__global__ void bn_stats(const float* __restrict__ x, int C, int per, int B,
                         const float* __restrict__ g, const float* __restrict__ bb,
                         float* __restrict__ a, float* __restrict__ s) {
  int c = blockIdx.x;
  int n = B * per;
  float sum = 0.f, sq = 0.f;
  for (int i = threadIdx.x; i < n; i += 256) {
    int b = i / per, p = i - b * per;
    float v = x[((size_t)b * C + c) * per + p];
    sum += v; sq += v * v;
  }
  __shared__ float S1[256], S2[256];
  S1[threadIdx.x] = sum; S2[threadIdx.x] = sq;
  __syncthreads();
  for (int off = 128; off > 0; off >>= 1) {
    if (threadIdx.x < off) { S1[threadIdx.x] += S1[threadIdx.x + off]; S2[threadIdx.x] += S2[threadIdx.x + off]; }
    __syncthreads();
  }
  if (threadIdx.x == 0) {
    float m = S1[0] / n;
    float var = S2[0] / n - m * m;
    float av = g[c] * rsqrtf(var + 1e-5f);
    a[c] = av; s[c] = bb[c] - m * av;
  }
}

__global__ void bn_apply_bf16(const float* __restrict__ x, bf16* __restrict__ y,
                              const float* __restrict__ a, const float* __restrict__ s,
                              int per, int C, size_t total) {
  size_t i = (size_t)blockIdx.x * 256 + threadIdx.x;
  if (i < total) {
    int ch = (int)((i / per) % C);
    y[i] = __float2bfloat16(a[ch] * x[i] + s[ch]);
  }
}

// ---------------- conv2 (4x4, 128->48), bn1 on load, relu on store ----------------
__global__ __launch_bounds__(192) void conv2_kernel(
    const float* __restrict__ pool, const float* __restrict__ w,
    const float* __restrict__ bias, const float* __restrict__ a1,
    const float* __restrict__ s1, float* __restrict__ out) {
  int rg = blockIdx.x, b = blockIdx.y;
  int r0 = rg * 4;
  __shared__ float L[128 * 7 * 15];
  int tid = threadIdx.x;
#pragma unroll
  for (int i = 0; i < 70; i++) {
    int idx = tid + i * 192;
    int c = idx / 105, rem = idx % 105;
    int r = rem / 15, col = rem % 15;
    L[idx] = pool[((size_t)(b * 128 + c)) * 225 + (r0 + r) * 15 + col] * a1[c] + s1[c];
  }
  __syncthreads();
  int oc = tid % 48, orow = tid / 48;
  float acc[12];
  float bv = bias[oc];
#pragma unroll
  for (int j = 0; j < 12; j++) acc[j] = bv;
  for (int c = 0; c < 128; c++) {
#pragma unroll
    for (int kr = 0; kr < 4; kr++) {
      float v[15];
#pragma unroll
      for (int q = 0; q < 15; q++) v[q] = L[(c * 7 + orow + kr) * 15 + q];
      const float* wp = &w[((size_t)(oc * 128 + c)) * 16 + kr * 4];
#pragma unroll
      for (int kc = 0; kc < 4; kc++) {
        float wv = wp[kc];
#pragma unroll
        for (int j = 0; j < 12; j++) acc[j] += wv * v[j + kc];
      }
    }
  }
  float* op = &out[((size_t)(b * 48 + oc)) * 144 + (r0 + orow) * 12];
#pragma unroll
  for (int j = 0; j < 12; j++) op[j] = fmaxf(acc[j], 0.f);
}

// ---------------- fc + log_softmax ----------------
__global__ __launch_bounds__(64) void fc_logsoftmax(
    const float* __restrict__ A, const float* __restrict__ W,
    const float* __restrict__ bias, float* __restrict__ out) {
  int b = blockIdx.x, lane = threadIdx.x;
  float acc[10] = {};
  for (int k = lane; k < 4096; k += 64) {
    float x = A[(size_t)b * 4096 + k];
#pragma unroll
    for (int o = 0; o < 10; o++) acc[o] += x * W[o * 4096 + k];
  }
#pragma unroll
  for (int o = 0; o < 10; o++)
    for (int off = 32; off > 0; off >>= 1) acc[o] += __shfl_down(acc[o], off);
  if (lane == 0) {
    float l[10];
    float m = -3.4e38f;
#pragma unroll
    for (int o = 0; o < 10; o++) { l[o] = acc[o] + bias[o]; m = fmaxf(m, l[o]); }
    float se = 0.f;
#pragma unroll
    for (int o = 0; o < 10; o++) se += expf(l[o] - m);
    float ls = logf(se);
#pragma unroll
    for (int o = 0; o < 10; o++) out[b * 10 + o] = l[o] - m - ls;
  }
}

__global__ void zero_k(float* __restrict__ p, size_t n) {
  size_t i = (size_t)blockIdx.x * 256 + threadIdx.x;
  if (i < n) p[i] = 0.f;
}

extern "C" void kernel_launch(void* const* d_in, const int* in_sizes, int n_in,
                              void* d_out, int out_size, void* d_ws, size_t ws_size,
                              hipStream_t stream) {
  const float* X    = (const float*)d_in[0];
  const float* c1w  = (const float*)d_in[1];
  const float* c1b  = (const float*)d_in[2];
  const float* bn1g = (const float*)d_in[3];
  const float* bn1b = (const float*)d_in[4];
  const float* c2w  = (const float*)d_in[5];
  const float* c2b  = (const float*)d_in[6];
  const float* bn2g = (const float*)d_in[7];
  const float* bn2b = (const float*)d_in[8];
  const float *Wih[4], *Whh[4], *bih[4], *bhh[4];
  for (int i = 0; i < 4; i++) {
    Wih[i] = (const float*)d_in[9 + 4 * i];
    Whh[i] = (const float*)d_in[10 + 4 * i];
    bih[i] = (const float*)d_in[11 + 4 * i];
    bhh[i] = (const float*)d_in[12 + 4 * i];
  }
  const float* d1w = (const float*)d_in[25];
  const float* d1b = (const float*)d_in[26];
  const float* d2w = (const float*)d_in[27];
  const float* d2b = (const float*)d_in[28];
  const float* fcw = (const float*)d_in[29];
  const float* fcb = (const float*)d_in[30];
  float* out = (float*)d_out;

  // ---- workspace layout (~294 MB) ----
  char* p = (char*)d_ws;
  float* v_fw = (float*)p;  p += (size_t)64 * 512 * 48 * 4;         // 6.3 MB
  char* R = p;              p += (size_t)167772160;                  // xg region (2x 83.9MB)
  bf16* xgA = (bf16*)R;
  bf16* xgB = xgA + (size_t)41943040;
  bf16* h_fw = (bf16*)p;    p += (size_t)64 * 512 * 640 * 2;         // 41.9 MB
  bf16* hfm  = (bf16*)p;    p += (size_t)512 * 40960 * 2;            // 41.9 MB
  bf16* wih3b = (bf16*)p;   p += (size_t)1280 * 640 * 2;
  bf16* wih4b = (bf16*)p;   p += (size_t)1280 * 640 * 2;
  bf16* whhb[4];
  for (int i = 0; i < 4; i++) { whhb[i] = (bf16*)p; p += (size_t)1280 * 320 * 2; }
  float* states = (float*)p; p += (size_t)3932160;                   // c (f32) + h hi/lo pp (bf16)
  float* P = (float*)p;      p += (size_t)4 * 512 * 2048 * 4;        // 16.8 MB split-K partials
  float* outcat = (float*)p; p += (size_t)512 * 4096 * 4;            // 8.4 MB
  float* bnp = (float*)p;    p += 2048;
  // conv aliases inside R (dead after dense1):
  float* pool   = (float*)R;                                         // 59.0 MB
  float* c2out  = (float*)(R + 58982400);                            // 14.2 MB
  bf16*  c2outb = (bf16*)(R + 58982400 + 14155776);                  // 7.1 MB
  bf16*  d2wb   = (bf16*)(R + 58982400 + 14155776 + 7077888);        // 28.3 MB
  bf16*  d1wb   = (bf16*)R;                                          // 167.8 MB (whole R)
  float* a1 = bnp, *s1 = bnp + 128, *a2 = bnp + 256, *s2 = bnp + 304;

  float* cA = states;
  float* cB = cA + 163840;
  bf16* hb = (bf16*)(cB + 163840);
  bf16* hA0h = hb;             bf16* hA0l = hb + 163840;
  bf16* hA1h = hb + 327680;    bf16* hA1l = hb + 491520;
  bf16* hB0h = hb + 655360;    bf16* hB0l = hb + 819200;
  bf16* hB1h = hb + 983040;    bf16* hB1l = hb + 1146880;

  // 1) patches + small weight conversions
  patch_kernel<<<6144, 256, 0, stream>>>(X, v_fw);
  for (int i = 0; i < 4; i++)
    cvt_f32_bf16_k<<<400, 256, 0, stream>>>(Whh[i], whhb[i], 102400);
  cvt_f32_bf16_k<<<800, 256, 0, stream>>>(Wih[2], wih3b, 204800);
  cvt_f32_bf16_k<<<800, 256, 0, stream>>>(Wih[3], wih4b, 204800);

  // 2) input projections for LSTM 1/2 (K=48, legacy fp32 gemm, bf16 out)
  gemm_nt<bf16, false><<<dim3(20, 512), 256, 0, stream>>>(v_fw, Wih[0], bih[0], bhh[0], xgA, 32768, 1280, 48, 1280);
  gemm_nt<bf16, false><<<dim3(20, 512), 256, 0, stream>>>(v_fw, Wih[1], bih[1], bhh[1], xgB, 32768, 1280, 48, 1280);

  // 3) phase A scan
  zero_k<<<3840, 256, 0, stream>>>(states, (size_t)983040);
  for (int t = 0; t < 64; t++) {
    const bf16* xf = xgA + (size_t)t * 655360;
    const bf16* xr = xgB + (size_t)(63 - t) * 655360;
    bf16* oA = h_fw + (size_t)t * 327680;
    if (t & 1)
      lstm_step_mfma<<<dim3(10, 8, 2), 256, 0, stream>>>(xf, xr, whhb[0], whhb[1],
          hA1h, hA1l, hA0h, hA0l, cA, hB1h, hB1l, hB0h, hB0l, cB, oA, oA + 320, 640);
    else
      lstm_step_mfma<<<dim3(10, 8, 2), 256, 0, stream>>>(xf, xr, whhb[0], whhb[1],
          hA0h, hA0l, hA1h, hA1l, cA, hB0h, hB0l, hB1h, hB1l, cB, oA, oA + 320, 640);
  }

  // 4) input projections for LSTM 3/4 (MFMA, overwrite xg region)
  gemm_mfma<bf16, false, false><<<dim3(10, 256, 1), 256, 0, stream>>>(h_fw, wih3b, bih[2], bhh[2], xgA, 32768, 1280, 640, 1280, 0);
  gemm_mfma<bf16, false, false><<<dim3(10, 256, 1), 256, 0, stream>>>(h_fw, wih4b, bih[3], bhh[3], xgB, 32768, 1280, 640, 1280, 0);

  // 5) phase B scan -> hfm
  zero_k<<<3840, 256, 0, stream>>>(states, (size_t)983040);
  for (int t = 0; t < 64; t++) {
    const bf16* xf = xgA + (size_t)t * 655360;
    const bf16* xr = xgB + (size_t)(63 - t) * 655360;
    bf16* oA = hfm + (size_t)t * 640;
    if (t & 1)
      lstm_step_mfma<<<dim3(10, 8, 2), 256, 0, stream>>>(xf, xr, whhb[2], whhb[3],
          hA1h, hA1l, hA0h, hA0l, cA, hB1h, hB1l, hB0h, hB0l, cB, oA, oA + 320, 40960);
    else
      lstm_step_mfma<<<dim3(10, 8, 2), 256, 0, stream>>>(xf, xr, whhb[2], whhb[3],
          hA0h, hA0l, hA1h, hA1l, cA, hB0h, hB0l, hB1h, hB1l, cB, oA, oA + 320, 40960);
  }

  // 6) dense1 (split-K=4) -> outcat[:, 0:2048]
  cvt_f32_bf16_k<<<81920, 256, 0, stream>>>(d1w, d1wb, 20971520);
  gemm_mfma<float, false, true><<<dim3(16, 4, 4), 256, 0, stream>>>(hfm, d1wb, nullptr, nullptr, P, 512, 2048, 40960, 2048, 10240);
  splitk_reduce<<<4096, 256, 0, stream>>>(P, d1b, outcat, 1048576, 2048, 4096, 4);

  // 7) conv branch (d1wb dead -> pool/c2out alias R)
  conv1_pool<<<512, 256, 0, stream>>>(X, c1w, c1b, pool);
  bn_stats<<<128, 256, 0, stream>>>(pool, 128, 225, 512, bn1g, bn1b, a1, s1);
  conv2_kernel<<<dim3(3, 512), 192, 0, stream>>>(pool, c2w, c2b, a1, s1, c2out);
  bn_stats<<<48, 256, 0, stream>>>(c2out, 48, 144, 512, bn2g, bn2b, a2, s2);
  bn_apply_bf16<<<13824, 256, 0, stream>>>(c2out, c2outb, a2, s2, 144, 48, (size_t)3538944);

  // 8) dense2 (split-K=4) -> outcat[:, 2048:4096]
  cvt_f32_bf16_k<<<13824, 256, 0, stream>>>(d2w, d2wb, 3538944);
  gemm_mfma<float, false, true><<<dim3(16, 4, 4), 256, 0, stream>>>(c2outb, d2wb, nullptr, nullptr, P, 512, 2048, 6912, 2048, 1728);
  splitk_reduce<<<4096, 256, 0, stream>>>(P, d2b, outcat + 2048, 1048576, 2048, 4096, 4);

  // 9) fc + log_softmax
  fc_logsoftmax<<<512, 64, 0, stream>>>(outcat, fcw, fcb, out);
}